// Round 2
// baseline (9439.658 us; speedup 1.0000x reference)
//
#include <hip/hip_runtime.h>
#include <stdint.h>

#define BB 64
#define TT 2048
#define EE 256
#define HH 512
#define SLICE 128   // h-rows per block
#define NSLICE 4

typedef unsigned long long u64;

__device__ __forceinline__ u64 pack_vt(float v, unsigned tag) {
    return ((u64)tag << 32) | (u64)__float_as_uint(v);
}

// 256 blocks (4 per batch), 256 threads. Thread layout for compute unchanged
// from round 1 (2 threads per row, 96 float4 of weights in regs).
// NEW: per-step wave role split to decouple vmcnt chains:
//   - producer lanes write tanh results to lds_pub (LDS), pre-barrier
//   - wave 3: reads lds_pub, issues ALL tagged u64 stores (never issues any
//     VMEM loads in the loop -> its store completions are never waited on)
//   - waves 0-2: stage x-prefetch into lds_x, then poll remote slices with a
//     CLEAN vmcnt (no own-store in their queue)
__global__ __launch_bounds__(256, 1)
void rnn_scan(const float* __restrict__ x,
              const int* __restrict__ lengths,
              const float* __restrict__ W_ih,
              const float* __restrict__ W_hh,
              const float* __restrict__ b_ih,
              const float* __restrict__ b_hh,
              const float* __restrict__ w_fc,
              const float* __restrict__ b_fc,
              float* __restrict__ out,   // [64] counts ++ [64][512] h_n
              u64* __restrict__ hx)      // [B][2][512] tagged values
{
    const int b   = blockIdx.x & 63;
    const int s   = blockIdx.x >> 6;
    const int tid = threadIdx.x;
    const int w   = tid >> 6;
    const int l   = tid & 63;
    const int rl  = (w << 5) + (l & 31);   // row within slice, 0..127
    const int row = s * SLICE + rl;        // global h row
    const int kh  = l >> 5;                // 0/1: which half of k/e range

    __shared__ float lds_h[HH];
    __shared__ float lds_x[EE];
    __shared__ float lds_pub[SLICE];

    // ---- one-time: weights into registers ----
    float4 whh[64];
#pragma unroll
    for (int i = 0; i < 64; ++i)
        whh[i] = *(const float4*)&W_hh[row * HH + kh * 256 + i * 4];
    float4 wih[32];
#pragma unroll
    for (int i = 0; i < 32; ++i)
        wih[i] = *(const float4*)&W_ih[row * EE + kh * 128 + i * 4];
    const float bsum = b_ih[row] + b_hh[row];

    float4 wf0 = make_float4(0.f, 0.f, 0.f, 0.f), wf1 = wf0;
    float bfc = 0.f;
    if (s == 0 && w == 0) {
        wf0 = *(const float4*)&w_fc[l * 8];
        wf1 = *(const float4*)&w_fc[l * 8 + 4];
        bfc = b_fc[0];
    }

    const int len = lengths[b];
    const float* xrow = x + (size_t)b * TT * EE;

    // init: h0 = 0, stage x[b][0]
    lds_h[tid]       = 0.f;
    lds_h[tid + 256] = 0.f;
    lds_x[tid]       = xrow[tid];
    __syncthreads();

    int count = 0;

#pragma unroll 1
    for (int t = 0; t < len; ++t) {
        // prefetch next x row — waves 0-2 only (keeps wave 3 load-free)
        float xn0 = 0.f, xn1 = 0.f;
        if (tid < 192 && t + 1 < TT) {
            xn0 = xrow[(size_t)(t + 1) * EE + tid];
            if (tid < 64) xn1 = xrow[(size_t)(t + 1) * EE + 192 + tid];
        }

        // ---- partial dot: W_hh slice · h  +  W_ih slice · x ----
        float4 a4 = make_float4(0.f, 0.f, 0.f, 0.f);
        const float4* hp = (const float4*)&lds_h[kh * 256];
#pragma unroll
        for (int i = 0; i < 64; ++i) {
            float4 hv = hp[i];
            a4.x = fmaf(whh[i].x, hv.x, a4.x);
            a4.y = fmaf(whh[i].y, hv.y, a4.y);
            a4.z = fmaf(whh[i].z, hv.z, a4.z);
            a4.w = fmaf(whh[i].w, hv.w, a4.w);
        }
        const float4* xp = (const float4*)&lds_x[kh * 128];
#pragma unroll
        for (int i = 0; i < 32; ++i) {
            float4 xv = xp[i];
            a4.x = fmaf(wih[i].x, xv.x, a4.x);
            a4.y = fmaf(wih[i].y, xv.y, a4.y);
            a4.z = fmaf(wih[i].z, xv.z, a4.z);
            a4.w = fmaf(wih[i].w, xv.w, a4.w);
        }
        float acc = (a4.x + a4.y) + (a4.z + a4.w);
        acc += __shfl_xor(acc, 32);        // combine the two k-halves

        const unsigned tag = (unsigned)(t + 1);
        u64* slot = hx + (size_t)((b * 2) + (t & 1)) * HH;

        if ((l & 32) == 0) {
            lds_pub[rl] = tanhf(acc + bsum);   // stage result for publisher wave
        }

        __syncthreads();   // [A] compute reads done; lds_pub filled

        if (w == 3) {
            // ---- publisher wave: own slice LDS -> lds_h + tagged global stores ----
            float2 v = *(const float2*)&lds_pub[2 * l];
            lds_h[s * SLICE + 2 * l]     = v.x;
            lds_h[s * SLICE + 2 * l + 1] = v.y;
            __hip_atomic_store(&slot[s * SLICE + 2 * l], pack_vt(v.x, tag),
                               __ATOMIC_RELAXED, __HIP_MEMORY_SCOPE_AGENT);
            __hip_atomic_store(&slot[s * SLICE + 2 * l + 1], pack_vt(v.y, tag),
                               __ATOMIC_RELAXED, __HIP_MEMORY_SCOPE_AGENT);
        } else {
            // ---- poller waves: stage x, then gather 3 remote slices ----
            lds_x[tid] = xn0;
            if (tid < 64) lds_x[192 + tid] = xn1;

            const int m0  = tid,        m1  = tid + 192;
            const int sp0 = (s + 1 + (m0 >> 7)) & 3, i0 = m0 & 127;
            const int sp1 = (s + 1 + (m1 >> 7)) & 3, i1 = m1 & 127;
            u64 va, vb;
            int guard = 0;
            do {
                va = __hip_atomic_load(&slot[sp0 * SLICE + i0],
                                       __ATOMIC_RELAXED, __HIP_MEMORY_SCOPE_AGENT);
                vb = __hip_atomic_load(&slot[sp1 * SLICE + i1],
                                       __ATOMIC_RELAXED, __HIP_MEMORY_SCOPE_AGENT);
            } while (((unsigned)(va >> 32) != tag || (unsigned)(vb >> 32) != tag)
                     && ++guard < (1 << 20));
            lds_h[sp0 * SLICE + i0] = __uint_as_float((unsigned)va);
            lds_h[sp1 * SLICE + i1] = __uint_as_float((unsigned)vb);
        }
        __syncthreads();   // [E] full h_t resident in lds_h

        // ---- fc logit count + h_n capture (block s==0 only) ----
        if (s == 0) {
            if (w == 0) {
                const float4* h4 = (const float4*)lds_h;
                float4 v0 = h4[l * 2], v1 = h4[l * 2 + 1];
                float pd = v0.x * wf0.x + v0.y * wf0.y + v0.z * wf0.z + v0.w * wf0.w
                         + v1.x * wf1.x + v1.y * wf1.y + v1.z * wf1.z + v1.w * wf1.w;
#pragma unroll
                for (int m = 1; m < 64; m <<= 1) pd += __shfl_xor(pd, m);
                if (l == 0 && (pd + bfc) > 0.f) count++;
            }
            if (t == len - 1) {
                out[64 + b * HH + tid * 2]     = lds_h[tid * 2];
                out[64 + b * HH + tid * 2 + 1] = lds_h[tid * 2 + 1];
            }
        }
    }

    if (s == 0 && tid == 0) out[b] = (float)count;
}

extern "C" void kernel_launch(void* const* d_in, const int* in_sizes, int n_in,
                              void* d_out, int out_size, void* d_ws, size_t ws_size,
                              hipStream_t stream) {
    const float* x       = (const float*)d_in[0];
    const int*   lengths = (const int*)  d_in[1];
    const float* W_ih    = (const float*)d_in[2];
    const float* W_hh    = (const float*)d_in[3];
    const float* b_ih    = (const float*)d_in[4];
    const float* b_hh    = (const float*)d_in[5];
    const float* w_fc    = (const float*)d_in[6];
    const float* b_fc    = (const float*)d_in[7];
    float* out = (float*)d_out;
    u64*   hx  = (u64*)d_ws;   // 64*2*512*8 = 512 KiB tagged exchange words

    hipLaunchKernelGGL(rnn_scan, dim3(BB * NSLICE), dim3(256), 0, stream,
                       x, lengths, W_ih, W_hh, b_ih, b_hh, w_fc, b_fc, out, hx);
}